// Round 12
// baseline (180.177 us; speedup 1.0000x reference)
//
#include <hip/hip_runtime.h>
#include <hip/hip_bf16.h>
#include <math.h>

// R12: three-stage split.
//   K1 make_patches: 2x2x3 corner patches, bf16, clamp folded (4 MB in d_ws).
//   K2 make_feats:   coords -> bilerp -> packed bf16 features (+bias word),
//                    32 MB in d_ws. Tiny kernel, high occupancy: the scattered
//                    gathers live HERE where TLP hides them.
//   K3 main:         zero interp. Layer-1 B-frag = direct broadcast load of
//                    featpk[pt*16+c] (16 unique addrs/wave, L1), double-
//                    buffered one group ahead. Then the R10/R11-proven chain:
//                    4 MFMA L1 -> packed leaky/pack -> cross-quad exchange
//                    (16 bpermute + cndmask) -> 8 MFMA L2 -> packed dot ->
//                    q-reduce -> sigmoid -> coalesced store. Zero LDS alloc.

#define NTHREADS 256
#define NB 4  // 64-point groups per wave

typedef __attribute__((ext_vector_type(8))) short bf16x8;  // 8 bf16 = 4 VGPRs
typedef __attribute__((ext_vector_type(4))) float f32x4;
typedef __attribute__((ext_vector_type(2))) float f32x2;
typedef __attribute__((ext_vector_type(4))) int i32x4;
typedef __attribute__((ext_vector_type(2))) int i32x2;

static __device__ __forceinline__ short f2bf(float f) {
    return __builtin_bit_cast(short, __float2bfloat16(f));  // setup only
}
// packed bf16 convert (gfx950 hw op, RNE)
static __device__ __forceinline__ int pk2(float lo, float hi) {
    int r;
    asm("v_cvt_pk_bf16_f32 %0, %1, %2" : "=v"(r) : "v"(lo), "v"(hi));
    return r;
}
static __device__ __forceinline__ float bflo(int u) {
    return __builtin_bit_cast(float, u << 16);
}
static __device__ __forceinline__ float bfhi(int u) {
    return __builtin_bit_cast(float, (int)(u & 0xffff0000));
}
static __device__ __forceinline__ f32x2 leaky2(f32x2 x) {
    return __builtin_elementwise_max(x, x * 0.01f);  // v_pk_mul + v_pk_max
}
static __device__ __forceinline__ int selperm(int addr, int pa, int pb,
                                              bool hi) {
    int va = __builtin_amdgcn_ds_bpermute(addr, pa);
    int vb = __builtin_amdgcn_ds_bpermute(addr, pb);
    return hi ? vb : va;
}

// ---- K1: pack 2x2 corner patches (bf16), both grids in one launch ----
__global__ __launch_bounds__(256) void make_patches(
    const float* __restrict__ gP, const float* __restrict__ gD,
    int* __restrict__ outP, int* __restrict__ outD) {
    int gid = blockIdx.x * 256 + threadIdx.x;  // 0..131071
    const float* g = (gid < 65536) ? gP : gD;
    int* po = (gid < 65536) ? outP : outD;
    int id = gid & 65535;
    int y0 = id >> 8, x0 = id & 255;
    int x1 = min(x0 + 1, 255), y1 = min(y0 + 1, 255);
    const float* tl = g + (y0 * 256 + x0) * 3;
    const float* tr = g + (y0 * 256 + x1) * 3;
    const float* bl = g + (y1 * 256 + x0) * 3;
    const float* br = g + (y1 * 256 + x1) * 3;
    i32x4 u0;
    i32x2 u1;
    u0[0] = pk2(tl[0], bl[0]);
    u0[1] = pk2(tl[1], bl[1]);
    u0[2] = pk2(tl[2], bl[2]);
    u0[3] = pk2(tr[0], br[0]);
    u1[0] = pk2(tr[1], br[1]);
    u1[1] = pk2(tr[2], br[2]);
    *(i32x4*)(po + id * 8) = u0;
    *(i32x2*)(po + id * 8 + 4) = u1;
}

static __device__ __forceinline__ void patch_issue(
    const int* __restrict__ tab, float px, float py, int* P, float& xf,
    float& yf) {
    float fx = px * 255.0f;
    float fy = py * 255.0f;
    int x0 = (int)fx;      // trunc, fx >= 0
    int y0 = (int)fy;
    xf = fx - floorf(fx);  // jnp.mod(fx,1.0), fx >= 0
    yf = fy - floorf(fy);
    int idx = (y0 << 8) | x0;
    i32x4 a = *(const i32x4*)(tab + idx * 8);
    i32x2 b = *(const i32x2*)(tab + idx * 8 + 4);
    P[0] = a[0]; P[1] = a[1]; P[2] = a[2];
    P[3] = a[3]; P[4] = b[0]; P[5] = b[1];
}

static __device__ __forceinline__ void patch_lerp(const int* P, float xf,
                                                  float yf, float* f) {
#pragma unroll
    for (int ch = 0; ch < 3; ++ch) {
        f32x2 L2 = {bflo(P[ch]), bfhi(P[ch])};          // {tl, bl}
        f32x2 R2 = {bflo(P[ch + 3]), bfhi(P[ch + 3])};  // {tr, br}
        f32x2 v = (R2 - L2) * xf + L2;                  // {top, bot}
        f[ch] = fmaf(yf, v.y - v.x, v.x);
    }
}

// ---- K2: coords -> packed bf16 features (+ bias word) ----
__global__ __launch_bounds__(256) void make_feats(
    const float2* __restrict__ pos2, const float2* __restrict__ dir2,
    const int* __restrict__ patP, const int* __restrict__ patD,
    i32x4* __restrict__ featpk, int npts) {
    int i = blockIdx.x * 256 + threadIdx.x;
    int stride = gridDim.x * 256;
#pragma unroll 1
    for (; i < npts; i += stride) {
        float2 pp = pos2[i], dd = dir2[i];
        int P[12];
        float fr[4];
        patch_issue(patP, pp.x, pp.y, P, fr[0], fr[1]);
        patch_issue(patD, dd.x, dd.y, P + 6, fr[2], fr[3]);
        float feat[6];
        patch_lerp(P, fr[0], fr[1], feat);
        patch_lerp(P + 6, fr[2], fr[3], feat + 3);
        i32x4 dv;
        dv[0] = pk2(feat[0], feat[1]);
        dv[1] = pk2(feat[2], feat[3]);
        dv[2] = pk2(feat[4], feat[5]);
        dv[3] = 0x3F80;  // k=6 bias = 1.0, k=7 = 0
        featpk[i] = dv;
    }
}

// ---- K3: MFMA MLP ----
__global__ __launch_bounds__(NTHREADS, 3) void mlp_mfma_kernel(
    const i32x4* __restrict__ featpk,
    const float* __restrict__ W1, const float* __restrict__ b1,
    const float* __restrict__ W2, const float* __restrict__ b2,
    const float* __restrict__ W3, const float* __restrict__ b3,
    float* __restrict__ out) {
    const int lane = threadIdx.x & 63;
    const int c = lane & 15;
    const int q = lane >> 4;

    // ---- resident weight fragments (16x16x32: A[m=lane&15][k=q*8+j]) ----
    bf16x8 A1f[4];
#pragma unroll
    for (int mt = 0; mt < 4; ++mt) {
        int f = mt * 16 + c;
        bf16x8 t;
#pragma unroll
        for (int j = 0; j < 8; ++j) {
            float v = 0.0f;
            if (q == 0) {
                if (j < 6) v = W1[f * 6 + j];
                else if (j == 6) v = b1[f];
            }
            t[j] = f2bf(v);
        }
        A1f[mt] = t;
    }
    bf16x8 A2f[2][4];
#pragma unroll
    for (int kt = 0; kt < 2; ++kt)
#pragma unroll
        for (int mt = 0; mt < 4; ++mt) {
            int n2 = mt * 16 + c;
            int k0 = kt * 32 + q * 8;
            bf16x8 t;
#pragma unroll
            for (int j = 0; j < 8; ++j) t[j] = f2bf(W2[n2 * 64 + k0 + j]);
            A2f[kt][mt] = t;
        }
    f32x4 ci[4], w3q[4];
#pragma unroll
    for (int mt = 0; mt < 4; ++mt)
#pragma unroll
        for (int r = 0; r < 4; ++r) {
            ci[mt][r] = b2[mt * 16 + q * 4 + r];
            w3q[mt][r] = W3[mt * 16 + q * 4 + r];
        }
    const float b3s = b3[0];
    const f32x4 zacc = {0.f, 0.f, 0.f, 0.f};

    // exchange lane addresses (bytes, lane*4): source lane = q_src*16 + c
    const int exA = ((((q & 1) * 2) * 16) + c) * 4;  // jj half 0
    const int exB = exA + 64;                        // jj half 1 (+16 lanes)
    const bool hi = (q >= 2);                        // selects mt = 2kt+1

    const long wave_global = (long)(blockIdx.x * 4) + (threadIdx.x >> 6);
    const long base0 = wave_global * (64L * NB);

    // ---- feature double-buffer: lane loads point pt*16+c's packed int4 ----
    // (16 unique addresses per wave, broadcast across quads -> L1-friendly)
    i32x4 bfc[4];
#pragma unroll
    for (int pt = 0; pt < 4; ++pt) bfc[pt] = featpk[base0 + pt * 16 + c];

#pragma unroll 1
    for (int ib = 0; ib < NB; ++ib) {
        const long base = base0 + ib * 64;

        // prefetch next group's features (consumed next iter)
        i32x4 bfn[4];
        {
            const long nb = base0 + (long)min(ib + 1, NB - 1) * 64;
#pragma unroll
            for (int pt = 0; pt < 4; ++pt) bfn[pt] = featpk[nb + pt * 16 + c];
        }

        // ---- 4 tiles of 16 points ----
        float s[4];
#pragma unroll
        for (int pt = 0; pt < 4; ++pt) {
            bf16x8 bfeat = __builtin_bit_cast(bf16x8, bfc[pt]);

            // layer 1: D1[f][p], f-rows q*4+r per mt
            f32x4 a1[4];
#pragma unroll
            for (int mt = 0; mt < 4; ++mt)
                a1[mt] = __builtin_amdgcn_mfma_f32_16x16x32_bf16(
                    A1f[mt], bfeat, zacc, 0, 0, 0);

            // leaky + pack pairs along f (packed f32 + v_cvt_pk_bf16_f32)
            int Pk[4][2];
#pragma unroll
            for (int mt = 0; mt < 4; ++mt) {
                f32x2 p0 = {a1[mt][0], a1[mt][1]};
                f32x2 p1 = {a1[mt][2], a1[mt][3]};
                p0 = leaky2(p0);
                p1 = leaky2(p1);
                Pk[mt][0] = pk2(p0.x, p0.y);
                Pk[mt][1] = pk2(p1.x, p1.y);
            }

            // exchange -> layer-2 B-frags, then 8 MFMAs (C init = b2)
            f32x4 a2[4];
#pragma unroll
            for (int kt = 0; kt < 2; ++kt) {
                i32x4 Q;
                Q[0] = selperm(exA, Pk[2 * kt][0], Pk[2 * kt + 1][0], hi);
                Q[1] = selperm(exA, Pk[2 * kt][1], Pk[2 * kt + 1][1], hi);
                Q[2] = selperm(exB, Pk[2 * kt][0], Pk[2 * kt + 1][0], hi);
                Q[3] = selperm(exB, Pk[2 * kt][1], Pk[2 * kt + 1][1], hi);
                bf16x8 bq = __builtin_bit_cast(bf16x8, Q);
#pragma unroll
                for (int mt = 0; mt < 4; ++mt)
                    a2[mt] = __builtin_amdgcn_mfma_f32_16x16x32_bf16(
                        A2f[kt][mt], bq, kt == 0 ? ci[mt] : a2[mt], 0, 0, 0);
            }

            // epilogue: packed leaky + packed dot with W3, then q-reduce
            f32x2 accv = {0.f, 0.f};
#pragma unroll
            for (int mt = 0; mt < 4; ++mt) {
                f32x2 x0 = {a2[mt][0], a2[mt][1]};
                f32x2 x1 = {a2[mt][2], a2[mt][3]};
                x0 = leaky2(x0);
                x1 = leaky2(x1);
                f32x2 w0 = {w3q[mt][0], w3q[mt][1]};
                f32x2 w1 = {w3q[mt][2], w3q[mt][3]};
                accv = x0 * w0 + accv;  // v_pk_fma_f32
                accv = x1 * w1 + accv;
            }
            float tt = accv.x + accv.y;
            tt += __shfl_xor(tt, 16, 64);
            tt += __shfl_xor(tt, 32, 64);
            s[pt] = tt;  // sum for point pt*16 + c, in all quads
        }

        // lane (c,q) emits point q*16 + c with value s[q]
        float sa = (q & 1) ? s[1] : s[0];
        float sb = (q & 1) ? s[3] : s[2];
        float v = (q & 2) ? sb : sa;
        v += b3s;
        v = 1.0f / (1.0f + __expf(-v));
        out[base + q * 16 + c] = v;

#pragma unroll
        for (int pt = 0; pt < 4; ++pt) bfc[pt] = bfn[pt];
    }
}

extern "C" void kernel_launch(void* const* d_in, const int* in_sizes, int n_in,
                              void* d_out, int out_size, void* d_ws,
                              size_t ws_size, hipStream_t stream) {
    const float* pos = (const float*)d_in[0];
    const float* dir = (const float*)d_in[1];
    const float* pos_grid = (const float*)d_in[2];
    const float* dir_grid = (const float*)d_in[3];
    const float* W1 = (const float*)d_in[4];
    const float* b1 = (const float*)d_in[5];
    const float* W2 = (const float*)d_in[6];
    const float* b2 = (const float*)d_in[7];
    const float* W3 = (const float*)d_in[8];
    const float* b3 = (const float*)d_in[9];
    float* out = (float*)d_out;

    const int n = in_sizes[0] / 2;  // points (2M)

    int* patP = (int*)d_ws;          // 65536 * 32 B = 2 MB
    int* patD = patP + 65536 * 8;    // 2 MB
    i32x4* featpk = (i32x4*)(patD + 65536 * 8);  // n * 16 B = 32 MB

    make_patches<<<512, 256, 0, stream>>>(pos_grid, dir_grid, patP, patD);
    make_feats<<<2048, 256, 0, stream>>>((const float2*)pos,
                                         (const float2*)dir, patP, patD,
                                         featpk, n);

    const int batches = n / 64;      // 32768
    const int waves = batches / NB;  // 8192
    const int blocks = waves / 4;    // 2048

    mlp_mfma_kernel<<<blocks, NTHREADS, 0, stream>>>(featpk, W1, b1, W2, b2,
                                                     W3, b3, out);
}

// Round 13
// 175.095 us; speedup vs baseline: 1.0290x; 1.0290x over previous
//
#include <hip/hip_runtime.h>
#include <hip/hip_bf16.h>
#include <math.h>

// R13: phase-major main kernel (4-tile structural ILP), LDS transpose back
//   (24 DS ops/group vs exchange's 128 VALU/DS ops), one RAW wait per GROUP.
//   __launch_bounds__(256,2): measured occupancy was 2.2 waves/SIMD anyway;
//   the register room buys real cross-tile interleaving.
//   K1 make_patches: 2x2x3 bf16 corner patches, clamp folded (4 MB d_ws).
//   K2 make_feats: split-half mapping (i, i+N/2) -> fully coalesced; 2 pts
//   per thread, all 8 gathers issued before lerps. 32 MB featpk in d_ws.
//   K3 main: load featpk (broadcast) -> phase-major L1 MFMA -> leaky/pack ->
//   LDS write -> read -> L2 MFMA (C=b2) -> packed dot W3 -> q-reduce ->
//   sigmoid -> coalesced store.

#define NTHREADS 256
#define NB 4                  // 64-point groups per wave
#define LSTRIDE 72            // shorts per row (144 B)
#define WAVE_L (64 * LSTRIDE) // 9216 B per wave

typedef __attribute__((ext_vector_type(8))) short bf16x8;  // 8 bf16 = 4 VGPRs
typedef __attribute__((ext_vector_type(4))) float f32x4;
typedef __attribute__((ext_vector_type(2))) float f32x2;
typedef __attribute__((ext_vector_type(4))) int i32x4;
typedef __attribute__((ext_vector_type(2))) int i32x2;

static __device__ __forceinline__ short f2bf(float f) {
    return __builtin_bit_cast(short, __float2bfloat16(f));  // setup only
}
// packed bf16 convert (gfx950 hw op, RNE)
static __device__ __forceinline__ int pk2(float lo, float hi) {
    int r;
    asm("v_cvt_pk_bf16_f32 %0, %1, %2" : "=v"(r) : "v"(lo), "v"(hi));
    return r;
}
static __device__ __forceinline__ float bflo(int u) {
    return __builtin_bit_cast(float, u << 16);
}
static __device__ __forceinline__ float bfhi(int u) {
    return __builtin_bit_cast(float, (int)(u & 0xffff0000));
}
static __device__ __forceinline__ f32x2 leaky2(f32x2 x) {
    return __builtin_elementwise_max(x, x * 0.01f);  // v_pk_mul + v_pk_max
}

// ---- K1: pack 2x2 corner patches (bf16), both grids in one launch ----
__global__ __launch_bounds__(256) void make_patches(
    const float* __restrict__ gP, const float* __restrict__ gD,
    int* __restrict__ outP, int* __restrict__ outD) {
    int gid = blockIdx.x * 256 + threadIdx.x;  // 0..131071
    const float* g = (gid < 65536) ? gP : gD;
    int* po = (gid < 65536) ? outP : outD;
    int id = gid & 65535;
    int y0 = id >> 8, x0 = id & 255;
    int x1 = min(x0 + 1, 255), y1 = min(y0 + 1, 255);
    const float* tl = g + (y0 * 256 + x0) * 3;
    const float* tr = g + (y0 * 256 + x1) * 3;
    const float* bl = g + (y1 * 256 + x0) * 3;
    const float* br = g + (y1 * 256 + x1) * 3;
    i32x4 u0;
    i32x2 u1;
    u0[0] = pk2(tl[0], bl[0]);
    u0[1] = pk2(tl[1], bl[1]);
    u0[2] = pk2(tl[2], bl[2]);
    u0[3] = pk2(tr[0], br[0]);
    u1[0] = pk2(tr[1], br[1]);
    u1[1] = pk2(tr[2], br[2]);
    *(i32x4*)(po + id * 8) = u0;
    *(i32x2*)(po + id * 8 + 4) = u1;
}

static __device__ __forceinline__ void patch_issue(
    const int* __restrict__ tab, float px, float py, int* P, float& xf,
    float& yf) {
    float fx = px * 255.0f;
    float fy = py * 255.0f;
    int x0 = (int)fx;      // trunc, fx >= 0
    int y0 = (int)fy;
    xf = fx - floorf(fx);  // jnp.mod(fx,1.0), fx >= 0
    yf = fy - floorf(fy);
    int idx = (y0 << 8) | x0;
    i32x4 a = *(const i32x4*)(tab + idx * 8);
    i32x2 b = *(const i32x2*)(tab + idx * 8 + 4);
    P[0] = a[0]; P[1] = a[1]; P[2] = a[2];
    P[3] = a[3]; P[4] = b[0]; P[5] = b[1];
}

static __device__ __forceinline__ void patch_lerp(const int* P, float xf,
                                                  float yf, float* f) {
#pragma unroll
    for (int ch = 0; ch < 3; ++ch) {
        f32x2 L2 = {bflo(P[ch]), bfhi(P[ch])};          // {tl, bl}
        f32x2 R2 = {bflo(P[ch + 3]), bfhi(P[ch + 3])};  // {tr, br}
        f32x2 v = (R2 - L2) * xf + L2;                  // {top, bot}
        f[ch] = fmaf(yf, v.y - v.x, v.x);
    }
}

// ---- K2: coords -> packed bf16 features; split-half for full coalescing ----
__global__ __launch_bounds__(256) void make_feats(
    const float2* __restrict__ pos2, const float2* __restrict__ dir2,
    const int* __restrict__ patP, const int* __restrict__ patD,
    i32x4* __restrict__ featpk, int half) {
    int i = blockIdx.x * 256 + threadIdx.x;  // 0..half-1
    float2 p0 = pos2[i], d0 = dir2[i];
    float2 p1 = pos2[i + half], d1 = dir2[i + half];
    int P0[12], P1[12];
    float f0[4], f1[4];
    patch_issue(patP, p0.x, p0.y, P0, f0[0], f0[1]);
    patch_issue(patD, d0.x, d0.y, P0 + 6, f0[2], f0[3]);
    patch_issue(patP, p1.x, p1.y, P1, f1[0], f1[1]);
    patch_issue(patD, d1.x, d1.y, P1 + 6, f1[2], f1[3]);
    float fe0[6], fe1[6];
    patch_lerp(P0, f0[0], f0[1], fe0);
    patch_lerp(P0 + 6, f0[2], f0[3], fe0 + 3);
    patch_lerp(P1, f1[0], f1[1], fe1);
    patch_lerp(P1 + 6, f1[2], f1[3], fe1 + 3);
    i32x4 dv0, dv1;
    dv0[0] = pk2(fe0[0], fe0[1]);
    dv0[1] = pk2(fe0[2], fe0[3]);
    dv0[2] = pk2(fe0[4], fe0[5]);
    dv0[3] = 0x3F80;  // k=6 bias = 1.0, k=7 = 0
    dv1[0] = pk2(fe1[0], fe1[1]);
    dv1[1] = pk2(fe1[2], fe1[3]);
    dv1[2] = pk2(fe1[4], fe1[5]);
    dv1[3] = 0x3F80;
    featpk[i] = dv0;
    featpk[i + half] = dv1;
}

// ---- K3: phase-major MFMA MLP ----
__global__ __launch_bounds__(NTHREADS, 2) void mlp_mfma_kernel(
    const i32x4* __restrict__ featpk,
    const float* __restrict__ W1, const float* __restrict__ b1,
    const float* __restrict__ W2, const float* __restrict__ b2,
    const float* __restrict__ W3, const float* __restrict__ b3,
    float* __restrict__ out) {
    __shared__ short lds_L[4 * WAVE_L];  // 36864 B
    const int w = threadIdx.x >> 6;
    const int lane = threadIdx.x & 63;
    const int c = lane & 15;
    const int q = lane >> 4;
    short* L = lds_L + w * WAVE_L;

    // ---- resident weight fragments (16x16x32: A[m=lane&15][k=q*8+j]) ----
    bf16x8 A1f[4];
#pragma unroll
    for (int mt = 0; mt < 4; ++mt) {
        int f = mt * 16 + c;
        bf16x8 t;
#pragma unroll
        for (int j = 0; j < 8; ++j) {
            float v = 0.0f;
            if (q == 0) {
                if (j < 6) v = W1[f * 6 + j];
                else if (j == 6) v = b1[f];
            }
            t[j] = f2bf(v);
        }
        A1f[mt] = t;
    }
    bf16x8 A2f[2][4];
#pragma unroll
    for (int kt = 0; kt < 2; ++kt)
#pragma unroll
        for (int mt = 0; mt < 4; ++mt) {
            int n2 = mt * 16 + c;
            int k0 = kt * 32 + q * 8;
            bf16x8 t;
#pragma unroll
            for (int j = 0; j < 8; ++j) t[j] = f2bf(W2[n2 * 64 + k0 + j]);
            A2f[kt][mt] = t;
        }
    f32x4 ci[4], w3q[4];
#pragma unroll
    for (int mt = 0; mt < 4; ++mt)
#pragma unroll
        for (int r = 0; r < 4; ++r) {
            ci[mt][r] = b2[mt * 16 + q * 4 + r];
            w3q[mt][r] = W3[mt * 16 + q * 4 + r];
        }
    const float b3s = b3[0];
    const f32x4 zacc = {0.f, 0.f, 0.f, 0.f};

    const long wave_global = (long)(blockIdx.x * 4) + w;
    const long base0 = wave_global * (64L * NB);

    // feature buffer: lane loads point pt*16+c's packed int4 (quad-broadcast)
    i32x4 bfc[4];
#pragma unroll
    for (int pt = 0; pt < 4; ++pt) bfc[pt] = featpk[base0 + pt * 16 + c];

#pragma unroll 1
    for (int ib = 0; ib < NB; ++ib) {
        const long base = base0 + ib * 64;

        // prefetch next group's features
        i32x4 bfn[4];
        {
            const long nb = base0 + (long)min(ib + 1, NB - 1) * 64;
#pragma unroll
            for (int pt = 0; pt < 4; ++pt) bfn[pt] = featpk[nb + pt * 16 + c];
        }

        // ---- phase 1: layer-1 MFMAs, ALL tiles (16 independent MFMAs) ----
        f32x4 a1[4][4];
#pragma unroll
        for (int pt = 0; pt < 4; ++pt) {
            bf16x8 bfeat = __builtin_bit_cast(bf16x8, bfc[pt]);
#pragma unroll
            for (int mt = 0; mt < 4; ++mt)
                a1[pt][mt] = __builtin_amdgcn_mfma_f32_16x16x32_bf16(
                    A1f[mt], bfeat, zacc, 0, 0, 0);
        }

        // ---- phase 2: leaky + pack + LDS transpose writes, ALL tiles ----
#pragma unroll
        for (int pt = 0; pt < 4; ++pt) {
            const int row = pt * 16 + c;
#pragma unroll
            for (int mt = 0; mt < 4; ++mt) {
                f32x2 p0 = {a1[pt][mt][0], a1[pt][mt][1]};
                f32x2 p1 = {a1[pt][mt][2], a1[pt][mt][3]};
                p0 = leaky2(p0);
                p1 = leaky2(p1);
                i32x2 wv;
                wv[0] = pk2(p0.x, p0.y);
                wv[1] = pk2(p1.x, p1.y);
                *(i32x2*)(L + row * LSTRIDE + mt * 16 + q * 4) = wv;
            }
        }

        // ---- phase 3: LDS reads, ALL tiles (one RAW wait for the group) ----
        bf16x8 h0[4], h1[4];
#pragma unroll
        for (int pt = 0; pt < 4; ++pt) {
            const int row = pt * 16 + c;
            h0[pt] = *(const bf16x8*)(L + row * LSTRIDE + q * 8);
            h1[pt] = *(const bf16x8*)(L + row * LSTRIDE + 32 + q * 8);
        }

        // ---- phase 4: layer-2 MFMAs, ALL tiles (C init = b2) ----
        f32x4 a2[4][4];
#pragma unroll
        for (int pt = 0; pt < 4; ++pt)
#pragma unroll
            for (int mt = 0; mt < 4; ++mt) {
                f32x4 t0 = __builtin_amdgcn_mfma_f32_16x16x32_bf16(
                    A2f[0][mt], h0[pt], ci[mt], 0, 0, 0);
                a2[pt][mt] = __builtin_amdgcn_mfma_f32_16x16x32_bf16(
                    A2f[1][mt], h1[pt], t0, 0, 0, 0);
            }

        // ---- phase 5: epilogue per tile ----
        float s[4];
#pragma unroll
        for (int pt = 0; pt < 4; ++pt) {
            f32x2 accv = {0.f, 0.f};
#pragma unroll
            for (int mt = 0; mt < 4; ++mt) {
                f32x2 x0 = {a2[pt][mt][0], a2[pt][mt][1]};
                f32x2 x1 = {a2[pt][mt][2], a2[pt][mt][3]};
                x0 = leaky2(x0);
                x1 = leaky2(x1);
                f32x2 w0 = {w3q[mt][0], w3q[mt][1]};
                f32x2 w1 = {w3q[mt][2], w3q[mt][3]};
                accv = x0 * w0 + accv;  // v_pk_fma_f32
                accv = x1 * w1 + accv;
            }
            float tt = accv.x + accv.y;
            tt += __shfl_xor(tt, 16, 64);
            tt += __shfl_xor(tt, 32, 64);
            s[pt] = tt;
        }

        // lane (c,q) emits point q*16 + c with value s[q]
        float sa = (q & 1) ? s[1] : s[0];
        float sb = (q & 1) ? s[3] : s[2];
        float v = (q & 2) ? sb : sa;
        v += b3s;
        v = 1.0f / (1.0f + __expf(-v));
        out[base + q * 16 + c] = v;

#pragma unroll
        for (int pt = 0; pt < 4; ++pt) bfc[pt] = bfn[pt];
    }
}

extern "C" void kernel_launch(void* const* d_in, const int* in_sizes, int n_in,
                              void* d_out, int out_size, void* d_ws,
                              size_t ws_size, hipStream_t stream) {
    const float* pos = (const float*)d_in[0];
    const float* dir = (const float*)d_in[1];
    const float* pos_grid = (const float*)d_in[2];
    const float* dir_grid = (const float*)d_in[3];
    const float* W1 = (const float*)d_in[4];
    const float* b1 = (const float*)d_in[5];
    const float* W2 = (const float*)d_in[6];
    const float* b2 = (const float*)d_in[7];
    const float* W3 = (const float*)d_in[8];
    const float* b3 = (const float*)d_in[9];
    float* out = (float*)d_out;

    const int n = in_sizes[0] / 2;  // points (2M)

    int* patP = (int*)d_ws;                      // 2 MB
    int* patD = patP + 65536 * 8;                // 2 MB
    i32x4* featpk = (i32x4*)(patD + 65536 * 8);  // n * 16 B = 32 MB

    make_patches<<<512, 256, 0, stream>>>(pos_grid, dir_grid, patP, patD);
    make_feats<<<(n / 2) / 256, 256, 0, stream>>>(
        (const float2*)pos, (const float2*)dir, patP, patD, featpk, n / 2);

    const int batches = n / 64;      // 32768
    const int waves = batches / NB;  // 8192
    const int blocks = waves / 4;    // 2048

    mlp_mfma_kernel<<<blocks, NTHREADS, 0, stream>>>(featpk, W1, b1, W2, b2,
                                                     W3, b3, out);
}

// Round 14
// 156.799 us; speedup vs baseline: 1.1491x; 1.1167x over previous
//
#include <hip/hip_runtime.h>
#include <hip/hip_bf16.h>
#include <math.h>

// R14: fused phase-major kernel.
//   = R13's phase-major MFMA core (LDS transpose, one RAW wait per group,
//     packed leaky/pack/dot ops, (256,2) no-spill)
//   + R11's interp pipeline fused back in (patch table gathers issued one
//     group ahead, coords two ahead, features -> bpermute B-frags).
//   Kills make_feats' 43 us + 64 MB featpk round-trip (R13's split cost).

#define NTHREADS 256
#define NB 4                  // 64-point groups per wave
#define LSTRIDE 72            // shorts per row (144 B)
#define WAVE_L (64 * LSTRIDE) // 9216 B per wave

typedef __attribute__((ext_vector_type(8))) short bf16x8;  // 8 bf16 = 4 VGPRs
typedef __attribute__((ext_vector_type(4))) float f32x4;
typedef __attribute__((ext_vector_type(2))) float f32x2;
typedef __attribute__((ext_vector_type(4))) int i32x4;
typedef __attribute__((ext_vector_type(2))) int i32x2;

static __device__ __forceinline__ short f2bf(float f) {
    return __builtin_bit_cast(short, __float2bfloat16(f));  // setup only
}
// packed bf16 convert (gfx950 hw op, RNE)
static __device__ __forceinline__ int pk2(float lo, float hi) {
    int r;
    asm("v_cvt_pk_bf16_f32 %0, %1, %2" : "=v"(r) : "v"(lo), "v"(hi));
    return r;
}
static __device__ __forceinline__ float bflo(int u) {
    return __builtin_bit_cast(float, u << 16);
}
static __device__ __forceinline__ float bfhi(int u) {
    return __builtin_bit_cast(float, (int)(u & 0xffff0000));
}
static __device__ __forceinline__ f32x2 leaky2(f32x2 x) {
    return __builtin_elementwise_max(x, x * 0.01f);  // v_pk_mul + v_pk_max
}

// ---- K1: pack 2x2 corner patches (bf16), both grids in one launch ----
__global__ __launch_bounds__(256) void make_patches(
    const float* __restrict__ gP, const float* __restrict__ gD,
    int* __restrict__ outP, int* __restrict__ outD) {
    int gid = blockIdx.x * 256 + threadIdx.x;  // 0..131071
    const float* g = (gid < 65536) ? gP : gD;
    int* po = (gid < 65536) ? outP : outD;
    int id = gid & 65535;
    int y0 = id >> 8, x0 = id & 255;
    int x1 = min(x0 + 1, 255), y1 = min(y0 + 1, 255);
    const float* tl = g + (y0 * 256 + x0) * 3;
    const float* tr = g + (y0 * 256 + x1) * 3;
    const float* bl = g + (y1 * 256 + x0) * 3;
    const float* br = g + (y1 * 256 + x1) * 3;
    i32x4 u0;
    i32x2 u1;
    u0[0] = pk2(tl[0], bl[0]);
    u0[1] = pk2(tl[1], bl[1]);
    u0[2] = pk2(tl[2], bl[2]);
    u0[3] = pk2(tr[0], br[0]);
    u1[0] = pk2(tr[1], br[1]);
    u1[1] = pk2(tr[2], br[2]);
    *(i32x4*)(po + id * 8) = u0;
    *(i32x2*)(po + id * 8 + 4) = u1;
}

static __device__ __forceinline__ void patch_issue(
    const int* __restrict__ tab, float px, float py, int* P, float& xf,
    float& yf) {
    float fx = px * 255.0f;
    float fy = py * 255.0f;
    int x0 = (int)fx;      // trunc, fx >= 0
    int y0 = (int)fy;
    xf = fx - floorf(fx);  // jnp.mod(fx,1.0), fx >= 0
    yf = fy - floorf(fy);
    int idx = (y0 << 8) | x0;
    i32x4 a = *(const i32x4*)(tab + idx * 8);
    i32x2 b = *(const i32x2*)(tab + idx * 8 + 4);
    P[0] = a[0]; P[1] = a[1]; P[2] = a[2];
    P[3] = a[3]; P[4] = b[0]; P[5] = b[1];
}

static __device__ __forceinline__ void patch_lerp(const int* P, float xf,
                                                  float yf, float* f) {
#pragma unroll
    for (int ch = 0; ch < 3; ++ch) {
        f32x2 L2 = {bflo(P[ch]), bfhi(P[ch])};          // {tl, bl}
        f32x2 R2 = {bflo(P[ch + 3]), bfhi(P[ch + 3])};  // {tr, br}
        f32x2 v = (R2 - L2) * xf + L2;                  // {top, bot}
        f[ch] = fmaf(yf, v.y - v.x, v.x);
    }
}

// ---- K2: fused phase-major MFMA MLP with inline interp ----
__global__ __launch_bounds__(NTHREADS, 2) void mlp_mfma_kernel(
    const float* __restrict__ pos, const float* __restrict__ dir,
    const int* __restrict__ patP, const int* __restrict__ patD,
    const float* __restrict__ W1, const float* __restrict__ b1,
    const float* __restrict__ W2, const float* __restrict__ b2,
    const float* __restrict__ W3, const float* __restrict__ b3,
    float* __restrict__ out) {
    __shared__ short lds_L[4 * WAVE_L];  // 36864 B
    const int w = threadIdx.x >> 6;
    const int lane = threadIdx.x & 63;
    const int c = lane & 15;
    const int q = lane >> 4;
    short* L = lds_L + w * WAVE_L;

    // ---- resident weight fragments (16x16x32: A[m=lane&15][k=q*8+j]) ----
    bf16x8 A1f[4];
#pragma unroll
    for (int mt = 0; mt < 4; ++mt) {
        int f = mt * 16 + c;
        bf16x8 t;
#pragma unroll
        for (int j = 0; j < 8; ++j) {
            float v = 0.0f;
            if (q == 0) {
                if (j < 6) v = W1[f * 6 + j];
                else if (j == 6) v = b1[f];
            }
            t[j] = f2bf(v);
        }
        A1f[mt] = t;
    }
    bf16x8 A2f[2][4];
#pragma unroll
    for (int kt = 0; kt < 2; ++kt)
#pragma unroll
        for (int mt = 0; mt < 4; ++mt) {
            int n2 = mt * 16 + c;
            int k0 = kt * 32 + q * 8;
            bf16x8 t;
#pragma unroll
            for (int j = 0; j < 8; ++j) t[j] = f2bf(W2[n2 * 64 + k0 + j]);
            A2f[kt][mt] = t;
        }
    f32x4 ci[4], w3q[4];
#pragma unroll
    for (int mt = 0; mt < 4; ++mt)
#pragma unroll
        for (int r = 0; r < 4; ++r) {
            ci[mt][r] = b2[mt * 16 + q * 4 + r];
            w3q[mt][r] = W3[mt * 16 + q * 4 + r];
        }
    const float b3s = b3[0];
    const int dbias = 0x3F80;  // {bf16(1.0), bf16(0.0)}: k=6 bias, k=7 zero
    const f32x4 zacc = {0.f, 0.f, 0.f, 0.f};

    const long wave_global = (long)(blockIdx.x * 4) + w;
    const long base0 = wave_global * (64L * NB);
    const float2* pos2 = (const float2*)pos;
    const float2* dir2 = (const float2*)dir;

    // ---- interp pipeline: patches for group 0, coords for group 1 ----
    int PA[12];
    float frA[4];
    float2 cp1, cd1;
    {
        float2 c0p = pos2[base0 + lane], c0d = dir2[base0 + lane];
        cp1 = pos2[base0 + 64 + lane];
        cd1 = dir2[base0 + 64 + lane];
        patch_issue(patP, c0p.x, c0p.y, PA, frA[0], frA[1]);
        patch_issue(patD, c0d.x, c0d.y, PA + 6, frA[2], frA[3]);
    }

#pragma unroll 1
    for (int ib = 0; ib < NB; ++ib) {
        const long base = base0 + ib * 64;

        // ---- phase 0: features for CURRENT group (patches issued last iter)
        int d0, d1, d2;
        {
            float feat[6];
            patch_lerp(PA, frA[0], frA[1], feat);
            patch_lerp(PA + 6, frA[2], frA[3], feat + 3);
            d0 = pk2(feat[0], feat[1]);
            d1 = pk2(feat[2], feat[3]);
            d2 = pk2(feat[4], feat[5]);
        }
        // issue patches for group ib+1; refill coords for ib+2
        patch_issue(patP, cp1.x, cp1.y, PA, frA[0], frA[1]);
        patch_issue(patD, cd1.x, cd1.y, PA + 6, frA[2], frA[3]);
        {
            int mb = min(ib + 2, NB - 1);
            cp1 = pos2[base0 + mb * 64 + lane];
            cd1 = dir2[base0 + mb * 64 + lane];
        }

        // ---- phase 1: layer-1 MFMAs, ALL tiles (16 independent MFMAs) ----
        f32x4 a1[4][4];
#pragma unroll
        for (int pt = 0; pt < 4; ++pt) {
            const int fa = (pt * 16 + c) * 4;
            i32x4 bi;
            bi[0] = __builtin_amdgcn_ds_bpermute(fa, d0);
            bi[1] = __builtin_amdgcn_ds_bpermute(fa, d1);
            bi[2] = __builtin_amdgcn_ds_bpermute(fa, d2);
            bi[3] = dbias;
            bf16x8 bfeat = __builtin_bit_cast(bf16x8, bi);
#pragma unroll
            for (int mt = 0; mt < 4; ++mt)
                a1[pt][mt] = __builtin_amdgcn_mfma_f32_16x16x32_bf16(
                    A1f[mt], bfeat, zacc, 0, 0, 0);
        }

        // ---- phase 2: leaky + pack + LDS transpose writes, ALL tiles ----
#pragma unroll
        for (int pt = 0; pt < 4; ++pt) {
            const int row = pt * 16 + c;
#pragma unroll
            for (int mt = 0; mt < 4; ++mt) {
                f32x2 p0 = {a1[pt][mt][0], a1[pt][mt][1]};
                f32x2 p1 = {a1[pt][mt][2], a1[pt][mt][3]};
                p0 = leaky2(p0);
                p1 = leaky2(p1);
                i32x2 wv;
                wv[0] = pk2(p0.x, p0.y);
                wv[1] = pk2(p1.x, p1.y);
                *(i32x2*)(L + row * LSTRIDE + mt * 16 + q * 4) = wv;
            }
        }

        // ---- phase 3: LDS reads, ALL tiles (one RAW wait for the group) ----
        bf16x8 h0[4], h1[4];
#pragma unroll
        for (int pt = 0; pt < 4; ++pt) {
            const int row = pt * 16 + c;
            h0[pt] = *(const bf16x8*)(L + row * LSTRIDE + q * 8);
            h1[pt] = *(const bf16x8*)(L + row * LSTRIDE + 32 + q * 8);
        }

        // ---- phase 4: layer-2 MFMAs, ALL tiles (C init = b2) ----
        f32x4 a2[4][4];
#pragma unroll
        for (int pt = 0; pt < 4; ++pt)
#pragma unroll
            for (int mt = 0; mt < 4; ++mt) {
                f32x4 t0 = __builtin_amdgcn_mfma_f32_16x16x32_bf16(
                    A2f[0][mt], h0[pt], ci[mt], 0, 0, 0);
                a2[pt][mt] = __builtin_amdgcn_mfma_f32_16x16x32_bf16(
                    A2f[1][mt], h1[pt], t0, 0, 0, 0);
            }

        // ---- phase 5: epilogue per tile ----
        float s[4];
#pragma unroll
        for (int pt = 0; pt < 4; ++pt) {
            f32x2 accv = {0.f, 0.f};
#pragma unroll
            for (int mt = 0; mt < 4; ++mt) {
                f32x2 x0 = {a2[pt][mt][0], a2[pt][mt][1]};
                f32x2 x1 = {a2[pt][mt][2], a2[pt][mt][3]};
                x0 = leaky2(x0);
                x1 = leaky2(x1);
                f32x2 w0 = {w3q[mt][0], w3q[mt][1]};
                f32x2 w1 = {w3q[mt][2], w3q[mt][3]};
                accv = x0 * w0 + accv;  // v_pk_fma_f32
                accv = x1 * w1 + accv;
            }
            float tt = accv.x + accv.y;
            tt += __shfl_xor(tt, 16, 64);
            tt += __shfl_xor(tt, 32, 64);
            s[pt] = tt;
        }

        // lane (c,q) emits point q*16 + c with value s[q]
        float sa = (q & 1) ? s[1] : s[0];
        float sb = (q & 1) ? s[3] : s[2];
        float v = (q & 2) ? sb : sa;
        v += b3s;
        v = 1.0f / (1.0f + __expf(-v));
        out[base + q * 16 + c] = v;
    }
}

extern "C" void kernel_launch(void* const* d_in, const int* in_sizes, int n_in,
                              void* d_out, int out_size, void* d_ws,
                              size_t ws_size, hipStream_t stream) {
    const float* pos = (const float*)d_in[0];
    const float* dir = (const float*)d_in[1];
    const float* pos_grid = (const float*)d_in[2];
    const float* dir_grid = (const float*)d_in[3];
    const float* W1 = (const float*)d_in[4];
    const float* b1 = (const float*)d_in[5];
    const float* W2 = (const float*)d_in[6];
    const float* b2 = (const float*)d_in[7];
    const float* W3 = (const float*)d_in[8];
    const float* b3 = (const float*)d_in[9];
    float* out = (float*)d_out;

    int* patP = (int*)d_ws;        // 2 MB
    int* patD = patP + 65536 * 8;  // 2 MB

    make_patches<<<512, 256, 0, stream>>>(pos_grid, dir_grid, patP, patD);

    const int n = in_sizes[0] / 2;   // points (2M)
    const int batches = n / 64;      // 32768
    const int waves = batches / NB;  // 8192
    const int blocks = waves / 4;    // 2048

    mlp_mfma_kernel<<<blocks, NTHREADS, 0, stream>>>(
        pos, dir, patP, patD, W1, b1, W2, b2, W3, b3, out);
}